// Round 7
// baseline (506.277 us; speedup 1.0000x reference)
//
#include <hip/hip_runtime.h>
#include <hip/hip_bf16.h>

// Problem constants (from reference)
#define SCREEN_W 1280
#define SCREEN_H 720
#define TILE_L   16
#define NBW      80    // ceil(1280/16)
#define NBH      45    // ceil(720/16)
#define NUM_TILE 3600  // 80*45
#define N_POINTS 32768

typedef int v4i __attribute__((ext_vector_type(4)));

// ---------------------------------------------------------------------------
// Kernel A: per-point tile-index ranges packed into one u32:
//   ximin | ximax<<8 | yimin<<16 | yimax<<24   (half-open: ximin <= xi < ximax)
// overlap(tile xi,yi) <=> ximin <= xi < ximax && yimin <= yi < yimax
// [verified R4/R6: absmax 0]. Table: 32768 * 4 B = 128 KB in d_ws.
// ---------------------------------------------------------------------------
__global__ void aabb_kernel(const float* __restrict__ pos2d,
                            const float* __restrict__ radius,
                            unsigned int* __restrict__ pk) {
    int t = blockIdx.x * blockDim.x + threadIdx.x;   // thread handles 4 points
    int n = t * 4;
    if (n >= N_POINTS) return;

    const float4* p4 = (const float4*)(pos2d + 2 * n);
    float4 p01 = p4[0];   // x0 y0 x1 y1
    float4 p23 = p4[1];   // x2 y2 x3 y3
    float4 r   = *(const float4*)(radius + n);

    float xs[4] = {p01.x, p01.z, p23.x, p23.z};
    float ys[4] = {p01.y, p01.w, p23.y, p23.w};
    float rs[4] = {r.x, r.y, r.z, r.w};

    uint4 outp;
    unsigned int* op = &outp.x;
#pragma unroll
    for (int j = 0; j < 4; ++j) {
        float x = xs[j], y = ys[j], rr = rs[j];
        int xmin = (int)fminf(fmaxf(x - rr, 0.0f), (float)SCREEN_W);
        int ymin = (int)fminf(fmaxf(y - rr, 0.0f), (float)SCREEN_H);
        int xmax = (int)fminf(fmaxf(x + rr, 0.0f), (float)SCREEN_W);
        int ymax = (int)fminf(fmaxf(y + rr, 0.0f), (float)SCREEN_H);
        unsigned int ximin = (unsigned int)(xmin >> 4);          // <= 80
        unsigned int ximax = (unsigned int)((xmax + 15) >> 4);   // <= 80
        unsigned int yimin = (unsigned int)(ymin >> 4);          // <= 45
        unsigned int yimax = (unsigned int)((ymax + 15) >> 4);   // <= 45
        op[j] = ximin | (ximax << 8) | (yimin << 16) | (yimax << 24);
    }
    *(uint4*)(pk + n) = outp;
}

// ---------------------------------------------------------------------------
// Kernel Z: zero-fill d_out — exact clone of the harness fill shape that
// measures 6.35 TB/s in this capture: grid-stride loop of dwordx4 stores,
// consecutive threads -> consecutive 16 B, long sequential streams per wave.
// ---------------------------------------------------------------------------
__global__ void __launch_bounds__(256)
zero_kernel(v4i* __restrict__ out4) {
    const int M = NUM_TILE * (N_POINTS / 4);   // 29,491,200 int4s
    v4i z = {0, 0, 0, 0};
    int stride = gridDim.x * blockDim.x;
    for (int i = blockIdx.x * blockDim.x + threadIdx.x; i < M; i += stride)
        out4[i] = z;
}

// ---------------------------------------------------------------------------
// Kernel S: scatter ones. One thread per point; iterate its tile rectangle
// (avg ~9, max 25 tiles) writing out[tile*N + n] = 1. ~300K scattered 4-B
// stores total (~0.25% density) — tiny vs the 472 MB bulk.
// ---------------------------------------------------------------------------
__global__ void __launch_bounds__(256)
scatter_kernel(const unsigned int* __restrict__ pk, int* __restrict__ out) {
    int n = blockIdx.x * blockDim.x + threadIdx.x;
    if (n >= N_POINTS) return;

    unsigned int w = pk[n];
    unsigned int ximin =  w        & 0xFFu;
    unsigned int ximax = (w >> 8)  & 0xFFu;
    unsigned int yimin = (w >> 16) & 0xFFu;
    unsigned int yimax =  w >> 24;

    for (unsigned int xi = ximin; xi < ximax; ++xi) {
        int* col = out + ((size_t)(xi * NBH)) * N_POINTS + n;
        for (unsigned int yi = yimin; yi < yimax; ++yi) {
            col[(size_t)yi * N_POINTS] = 1;
        }
    }
}

extern "C" void kernel_launch(void* const* d_in, const int* in_sizes, int n_in,
                              void* d_out, int out_size, void* d_ws, size_t ws_size,
                              hipStream_t stream) {
    const float* pos2d  = (const float*)d_in[0];
    const float* radius = (const float*)d_in[1];
    int* out = (int*)d_out;
    unsigned int* pk = (unsigned int*)d_ws;   // 32768 * 4 B = 128 KB

    // A: per-point packed tile ranges (8192 threads)
    aabb_kernel<<<dim3(8192 / 256), dim3(256), 0, stream>>>(pos2d, radius, pk);

    // Z: bulk zero-fill, proven fill shape (2048 blocks = 8 blocks/CU)
    zero_kernel<<<dim3(2048), dim3(256), 0, stream>>>((v4i*)out);

    // S: scatter the ~300K ones (one thread per point)
    scatter_kernel<<<dim3(N_POINTS / 256), dim3(256), 0, stream>>>(pk, out);
}

// Round 8
// 458.211 us; speedup vs baseline: 1.1049x; 1.1049x over previous
//
#include <hip/hip_runtime.h>
#include <hip/hip_bf16.h>

// Problem constants (from reference)
#define SCREEN_W 1280
#define SCREEN_H 720
#define TILE_L   16
#define NBW      80    // ceil(1280/16)
#define NBH      45    // ceil(720/16)
#define NUM_TILE 3600  // 80*45
#define N_POINTS 32768

typedef int v4i __attribute__((ext_vector_type(4)));

// ---------------------------------------------------------------------------
// Kernel A: per-point tile-index ranges packed into one u32:
//   ximin | ximax<<8 | yimin<<16 | yimax<<24   (half-open: ximin <= xi < ximax)
// overlap(tile xi,yi) <=> ximin <= xi < ximax && yimin <= yi < yimax
// [verified R4/R6: absmax 0]. Table: 32768 * 4 B = 128 KB in d_ws.
// ---------------------------------------------------------------------------
__global__ void aabb_kernel(const float* __restrict__ pos2d,
                            const float* __restrict__ radius,
                            unsigned int* __restrict__ pk) {
    int t = blockIdx.x * blockDim.x + threadIdx.x;   // thread handles 4 points
    int n = t * 4;
    if (n >= N_POINTS) return;

    const float4* p4 = (const float4*)(pos2d + 2 * n);
    float4 p01 = p4[0];   // x0 y0 x1 y1
    float4 p23 = p4[1];   // x2 y2 x3 y3
    float4 r   = *(const float4*)(radius + n);

    float xs[4] = {p01.x, p01.z, p23.x, p23.z};
    float ys[4] = {p01.y, p01.w, p23.y, p23.w};
    float rs[4] = {r.x, r.y, r.z, r.w};

    uint4 outp;
    unsigned int* op = &outp.x;
#pragma unroll
    for (int j = 0; j < 4; ++j) {
        float x = xs[j], y = ys[j], rr = rs[j];
        int xmin = (int)fminf(fmaxf(x - rr, 0.0f), (float)SCREEN_W);
        int ymin = (int)fminf(fmaxf(y - rr, 0.0f), (float)SCREEN_H);
        int xmax = (int)fminf(fmaxf(x + rr, 0.0f), (float)SCREEN_W);
        int ymax = (int)fminf(fmaxf(y + rr, 0.0f), (float)SCREEN_H);
        unsigned int ximin = (unsigned int)(xmin >> 4);          // <= 80
        unsigned int ximax = (unsigned int)((xmax + 15) >> 4);   // <= 80
        unsigned int yimin = (unsigned int)(ymin >> 4);          // <= 45
        unsigned int yimax = (unsigned int)((ymax + 15) >> 4);   // <= 45
        op[j] = ximin | (ximax << 8) | (yimin << 16) | (yimax << 24);
    }
    *(uint4*)(pk + n) = outp;
}

// ---------------------------------------------------------------------------
// Kernel B (R8): fused mask in the PROVEN fill shape — 2048 blocks x 256,
// grid-stride loop in LINEAR output order, one sequential 16-B store per
// iteration. tile = i>>13 is wave-uniform (wave spans 64 int4s; tile spans
// 8192) -> scalar div/mod. pk[q] load is L2-resident (128 KB table).
// This is the harness fill's access pattern (measured 6.35 TB/s in-capture)
// plus one L2-hit load + ~12 VALU per iteration.
// ---------------------------------------------------------------------------
__global__ void __launch_bounds__(256)
mask_kernel(const uint4* __restrict__ pk, v4i* __restrict__ out4) {
    const int M = NUM_TILE * (N_POINTS / 4);   // 29,491,200 int4s
    int stride = gridDim.x * blockDim.x;
    for (int i = blockIdx.x * blockDim.x + threadIdx.x; i < M; i += stride) {
        int tile = i >> 13;                    // / (N_POINTS/4)
        int q    = i & 8191;                   // uint4 index within tile
        unsigned int xi = (unsigned int)(tile / NBH);   // wave-uniform
        unsigned int yi = (unsigned int)(tile - (int)xi * NBH);

        uint4 p = pk[q];
        const unsigned int* pp = &p.x;
        v4i res;
#pragma unroll
        for (int j = 0; j < 4; ++j) {
            unsigned int w = pp[j];
            unsigned int ximin =  w        & 0xFFu;
            unsigned int ximax = (w >> 8)  & 0xFFu;
            unsigned int yimin = (w >> 16) & 0xFFu;
            unsigned int yimax =  w >> 24;
            res[j] = (xi >= ximin && xi < ximax && yi >= yimin && yi < yimax) ? 1 : 0;
        }
        out4[i] = res;   // plain sequential store (NT was neutral — R6)
    }
}

extern "C" void kernel_launch(void* const* d_in, const int* in_sizes, int n_in,
                              void* d_out, int out_size, void* d_ws, size_t ws_size,
                              hipStream_t stream) {
    const float* pos2d  = (const float*)d_in[0];
    const float* radius = (const float*)d_in[1];
    int* out = (int*)d_out;
    unsigned int* pk = (unsigned int*)d_ws;   // 32768 * 4 B = 128 KB

    // A: per-point packed tile ranges (8192 threads)
    aabb_kernel<<<dim3(8192 / 256), dim3(256), 0, stream>>>(pos2d, radius, pk);

    // B: fused mask, fill-shaped (2048 blocks = 8 blocks/CU, 56 iters/thread)
    mask_kernel<<<dim3(2048), dim3(256), 0, stream>>>((const uint4*)pk, (v4i*)out);
}

// Round 9
// 446.841 us; speedup vs baseline: 1.1330x; 1.0254x over previous
//
#include <hip/hip_runtime.h>
#include <hip/hip_bf16.h>

// Problem constants (from reference)
#define SCREEN_W 1280
#define SCREEN_H 720
#define TILE_L   16
#define NBW      80    // ceil(1280/16)
#define NBH      45    // ceil(720/16)
#define NUM_TILE 3600  // 80*45
#define N_POINTS 32768

typedef int v4i __attribute__((ext_vector_type(4)));

// ---------------------------------------------------------------------------
// Kernel A: per-point tile-index ranges packed into one u32:
//   ximin | ximax<<8 | yimin<<16 | yimax<<24   (half-open: ximin <= xi < ximax)
// overlap(tile xi,yi) <=> ximin <= xi < ximax && yimin <= yi < yimax
// [verified R4/R6/R8: absmax 0]. Table: 32768 * 4 B = 128 KB in d_ws.
// ---------------------------------------------------------------------------
__global__ void aabb_kernel(const float* __restrict__ pos2d,
                            const float* __restrict__ radius,
                            unsigned int* __restrict__ pk) {
    int t = blockIdx.x * blockDim.x + threadIdx.x;   // thread handles 4 points
    int n = t * 4;
    if (n >= N_POINTS) return;

    const float4* p4 = (const float4*)(pos2d + 2 * n);
    float4 p01 = p4[0];   // x0 y0 x1 y1
    float4 p23 = p4[1];   // x2 y2 x3 y3
    float4 r   = *(const float4*)(radius + n);

    float xs[4] = {p01.x, p01.z, p23.x, p23.z};
    float ys[4] = {p01.y, p01.w, p23.y, p23.w};
    float rs[4] = {r.x, r.y, r.z, r.w};

    uint4 outp;
    unsigned int* op = &outp.x;
#pragma unroll
    for (int j = 0; j < 4; ++j) {
        float x = xs[j], y = ys[j], rr = rs[j];
        int xmin = (int)fminf(fmaxf(x - rr, 0.0f), (float)SCREEN_W);
        int ymin = (int)fminf(fmaxf(y - rr, 0.0f), (float)SCREEN_H);
        int xmax = (int)fminf(fmaxf(x + rr, 0.0f), (float)SCREEN_W);
        int ymax = (int)fminf(fmaxf(y + rr, 0.0f), (float)SCREEN_H);
        unsigned int ximin = (unsigned int)(xmin >> 4);          // <= 80
        unsigned int ximax = (unsigned int)((xmax + 15) >> 4);   // <= 80
        unsigned int yimin = (unsigned int)(ymin >> 4);          // <= 45
        unsigned int yimax = (unsigned int)((ymax + 15) >> 4);   // <= 45
        op[j] = ximin | (ximax << 8) | (yimin << 16) | (yimax << 24);
    }
    *(uint4*)(pk + n) = outp;
}

// ---------------------------------------------------------------------------
// Kernel B (best measured — R6, 446.4 us): tile t (blockIdx.y), point chunk
// (blockIdx.x). One uint4 load per thread (4 packed points, L2-resident
// 128 KB table), byte-unpack compares vs (xi,yi), ONE plain 16-B store.
// Output layout: out[t * N_POINTS + n]  (tile-major [T, N]).
//
// Shape ledger (R3..R8): 4-load variant 490; this 447/446; yi-loop 459;
// zero+scatter 506; fill-clone grid-stride 458 — all alternatives within
// harness-fill variance; this is the measured optimum.
// ---------------------------------------------------------------------------
__global__ void __launch_bounds__(256)
mask_kernel(const uint4* __restrict__ pk, int* __restrict__ out) {
    int tile = blockIdx.y;
    int t = blockIdx.x * blockDim.x + threadIdx.x;   // thread index over uint4s
    int n = t * 4;                                    // first point index

    unsigned int xi = (unsigned int)(tile / NBH);
    unsigned int yi = (unsigned int)(tile - (int)xi * NBH);

    uint4 p = pk[t];
    const unsigned int* pp = &p.x;

    v4i res;
#pragma unroll
    for (int j = 0; j < 4; ++j) {
        unsigned int w = pp[j];
        unsigned int ximin =  w        & 0xFFu;
        unsigned int ximax = (w >> 8)  & 0xFFu;
        unsigned int yimin = (w >> 16) & 0xFFu;
        unsigned int yimax =  w >> 24;
        res[j] = (xi >= ximin && xi < ximax && yi >= yimin && yi < yimax) ? 1 : 0;
    }

    *(v4i*)(out + (size_t)tile * N_POINTS + n) = res;   // plain store (NT neutral, R6)
}

extern "C" void kernel_launch(void* const* d_in, const int* in_sizes, int n_in,
                              void* d_out, int out_size, void* d_ws, size_t ws_size,
                              hipStream_t stream) {
    const float* pos2d  = (const float*)d_in[0];
    const float* radius = (const float*)d_in[1];
    int* out = (int*)d_out;
    unsigned int* pk = (unsigned int*)d_ws;   // 32768 * 4 B = 128 KB

    // A: per-point packed tile ranges (8192 threads)
    aabb_kernel<<<dim3(8192 / 256), dim3(256), 0, stream>>>(pos2d, radius, pk);

    // B: 32768 / (256*4) = 32 chunks x 3600 tiles
    mask_kernel<<<dim3(32, NUM_TILE), dim3(256), 0, stream>>>((const uint4*)pk, out);
}